// Round 1
// baseline (1200.748 us; speedup 1.0000x reference)
//
#include <hip/hip_runtime.h>
#include <math.h>

// Problem constants (validated against in_sizes at runtime where possible)
#define NVOCAB 128

// ---------------------------------------------------------------------------
// K1: in-degree histogram (real edges only; self-loop added as +1 in k_dis)
__global__ void k_deg(const int* __restrict__ dst, int* __restrict__ degi, int E) {
    int i = blockIdx.x * 256 + threadIdx.x;
    if (i < E) atomicAdd(&degi[dst[i]], 1);
}

// K2: dis = rsqrt(deg), deg = in-degree + 1 (self loop), always >= 1
__global__ void k_dis(const int* __restrict__ degi, float* __restrict__ dis, int n) {
    int i = blockIdx.x * 256 + threadIdx.x;
    if (i < n) dis[i] = rsqrtf((float)(degi[i] + 1));
}

// K3: T1 = emb @ W1   [128,64]@[64,128] -> [128,128]
__global__ void k_t1(const float* __restrict__ emb, const float* __restrict__ W1,
                     float* __restrict__ T1) {
    int id = blockIdx.x * 256 + threadIdx.x;   // 0..16383
    int r = id >> 7, f = id & 127;
    float acc = 0.f;
#pragma unroll
    for (int k = 0; k < 64; ++k) acc += emb[r * 64 + k] * W1[k * 128 + f];
    T1[id] = acc;
}

// K4: per-dst vocab-weight accumulation.
//   w[dst][nid[src]] += dis[src]  for every edge (incl. self loops for i>=E)
__global__ void k_wacc(const int* __restrict__ src, const int* __restrict__ dst,
                       const int* __restrict__ nid, const float* __restrict__ dis,
                       float* __restrict__ w, int E, int n) {
    int i = blockIdx.x * 256 + threadIdx.x;
    if (i < E) {
        int s = src[i], d = dst[i];
        atomicAdd(&w[(size_t)d * 128 + nid[s]], dis[s]);
    } else if (i < E + n) {
        int v = i - E;
        atomicAdd(&w[(size_t)v * 128 + nid[v]], dis[v]);
    }
}

// K5: out1 = relu( dis[v] * (w[v] @ T1) + b1 )   [N,128]@[128,128]
__global__ __launch_bounds__(256) void k_layer1(
        const float* __restrict__ w, const float* __restrict__ T1,
        const float* __restrict__ dis, const float* __restrict__ b1,
        float* __restrict__ out1, int n) {
    __shared__ float sT1[128 * 128];
    const float4* T14 = (const float4*)T1;
    float4* s4 = (float4*)sT1;
    for (int i = threadIdx.x; i < 128 * 128 / 4; i += 256) s4[i] = T14[i];
    __syncthreads();
    int wid = threadIdx.x >> 6, lane = threadIdx.x & 63;
    float bl = b1[lane], bh = b1[64 + lane];
    for (int v = blockIdx.x * 4 + wid; v < n; v += gridDim.x * 4) {
        float wlo = w[(size_t)v * 128 + lane];
        float whi = w[(size_t)v * 128 + 64 + lane];
        float a0 = 0.f, a1 = 0.f;
#pragma unroll
        for (int k = 0; k < 64; ++k) {
            float wk = __shfl(wlo, k);
            a0 += wk * sT1[k * 128 + lane];
            a1 += wk * sT1[k * 128 + 64 + lane];
        }
#pragma unroll
        for (int k = 0; k < 64; ++k) {
            float wk = __shfl(whi, k);
            a0 += wk * sT1[(64 + k) * 128 + lane];
            a1 += wk * sT1[(64 + k) * 128 + 64 + lane];
        }
        float dv = dis[v];
        out1[(size_t)v * 128 + lane]      = fmaxf(dv * a0 + bl, 0.f);
        out1[(size_t)v * 128 + 64 + lane] = fmaxf(dv * a1 + bh, 0.f);
    }
}

// K6: g[v] = dis[v] * (out1[v] @ W2)   [N,128]@[128,64]; acc2 init = g (self loop)
__global__ __launch_bounds__(256) void k_layer2_transform(
        const float* __restrict__ out1, const float* __restrict__ W2,
        const float* __restrict__ dis,
        float* __restrict__ g, float* __restrict__ acc2, int n) {
    __shared__ float sW2[128 * 64];
    const float4* W24 = (const float4*)W2;
    float4* s4 = (float4*)sW2;
    for (int i = threadIdx.x; i < 128 * 64 / 4; i += 256) s4[i] = W24[i];
    __syncthreads();
    int wid = threadIdx.x >> 6, lane = threadIdx.x & 63;
    for (int v = blockIdx.x * 4 + wid; v < n; v += gridDim.x * 4) {
        float xlo = out1[(size_t)v * 128 + lane];
        float xhi = out1[(size_t)v * 128 + 64 + lane];
        float a = 0.f;
#pragma unroll
        for (int k = 0; k < 64; ++k) a += __shfl(xlo, k) * sW2[k * 64 + lane];
#pragma unroll
        for (int k = 0; k < 64; ++k) a += __shfl(xhi, k) * sW2[(64 + k) * 64 + lane];
        float val = dis[v] * a;
        g[(size_t)v * 64 + lane] = val;
        acc2[(size_t)v * 64 + lane] = val;
    }
}

// K7: edge scatter for layer 2: acc2[dst] += g[src]   (one wave per edge)
__global__ void k_agg2(const int* __restrict__ src, const int* __restrict__ dst,
                       const float* __restrict__ g, float* __restrict__ acc2, int E) {
    int wg = (blockIdx.x * 256 + threadIdx.x) >> 6;
    int lane = threadIdx.x & 63;
    if (wg >= E) return;
    int s = src[wg], d = dst[wg];
    atomicAdd(&acc2[(size_t)d * 64 + lane], g[(size_t)s * 64 + lane]);
}

// K8: x2 = relu(dis*acc2 + b2); pool into per-graph sums + counts
__global__ void k_pool(const float* __restrict__ acc2, const float* __restrict__ dis,
                       const float* __restrict__ b2, const int* __restrict__ batch,
                       float* __restrict__ pooled, float* __restrict__ counts, int n) {
    int v = (blockIdx.x * 256 + threadIdx.x) >> 6;
    int lane = threadIdx.x & 63;
    if (v >= n) return;
    float x = fmaxf(dis[v] * acc2[(size_t)v * 64 + lane] + b2[lane], 0.f);
    int b = batch[v];
    atomicAdd(&pooled[(size_t)b * 64 + lane], x);
    if (lane == 0) atomicAdd(&counts[b], 1.0f);
}

// K9: mean pool + fc + sigmoid  (one wave per graph)
__global__ void k_head(const float* __restrict__ pooled, const float* __restrict__ counts,
                       const float* __restrict__ fc_w, const float* __restrict__ fc_b,
                       float* __restrict__ out, int ngraphs) {
    int gi = (blockIdx.x * 256 + threadIdx.x) >> 6;
    int lane = threadIdx.x & 63;
    if (gi >= ngraphs) return;
    float c = fmaxf(counts[gi], 1.0f);
    float a = (pooled[(size_t)gi * 64 + lane] / c) * fc_w[lane];
#pragma unroll
    for (int off = 32; off >= 1; off >>= 1) a += __shfl_down(a, off);
    if (lane == 0) out[gi] = 1.0f / (1.0f + expf(-(a + fc_b[0])));
}

extern "C" void kernel_launch(void* const* d_in, const int* in_sizes, int n_in,
                              void* d_out, int out_size, void* d_ws, size_t ws_size,
                              hipStream_t stream) {
    const int*   nid   = (const int*)d_in[0];
    const int*   eidx  = (const int*)d_in[1];
    const int*   batch = (const int*)d_in[2];
    const float* emb   = (const float*)d_in[3];
    const float* W1    = (const float*)d_in[4];
    const float* b1    = (const float*)d_in[5];
    const float* W2    = (const float*)d_in[6];
    const float* b2    = (const float*)d_in[7];
    const float* fcw   = (const float*)d_in[8];
    const float* fcb   = (const float*)d_in[9];

    const int N = in_sizes[0];
    const int E = in_sizes[1] / 2;
    const int G = out_size;
    const int* src = eidx;
    const int* dst = eidx + E;

    // workspace carve-out (256B aligned)
    char* p = (char*)d_ws;
    auto alloc = [&](size_t bytes) {
        char* r = p;
        p += (bytes + 255) & ~(size_t)255;
        return r;
    };
    int*   degi   = (int*)  alloc((size_t)N * 4);
    float* dis    = (float*)alloc((size_t)N * 4);
    float* T1     = (float*)alloc(128 * 128 * 4);
    float* w      = (float*)alloc((size_t)N * 128 * 4);
    float* out1   = (float*)alloc((size_t)N * 128 * 4);
    float* acc2   = (float*)alloc((size_t)N * 64 * 4);
    float* pooled = (float*)alloc((size_t)G * 64 * 4);
    float* counts = (float*)alloc((size_t)G * 4);
    float* g = w;  // alias: w dead after k_layer1, g written in k_layer2_transform

    hipMemsetAsync(degi, 0, (size_t)N * 4, stream);
    hipMemsetAsync(w, 0, (size_t)N * 128 * 4, stream);
    hipMemsetAsync(pooled, 0, (size_t)G * 64 * 4, stream);
    hipMemsetAsync(counts, 0, (size_t)G * 4, stream);

    k_deg<<<(E + 255) / 256, 256, 0, stream>>>(dst, degi, E);
    k_dis<<<(N + 255) / 256, 256, 0, stream>>>(degi, dis, N);
    k_t1<<<64, 256, 0, stream>>>(emb, W1, T1);
    k_wacc<<<(E + N + 255) / 256, 256, 0, stream>>>(src, dst, nid, dis, w, E, N);
    k_layer1<<<2048, 256, 0, stream>>>(w, T1, dis, b1, out1, N);
    k_layer2_transform<<<2048, 256, 0, stream>>>(out1, W2, dis, g, acc2, N);
    {
        long long waves = (long long)E;
        long long blocks = (waves * 64 + 255) / 256;
        k_agg2<<<(int)blocks, 256, 0, stream>>>(src, dst, g, acc2, E);
    }
    k_pool<<<((long long)N * 64 + 255) / 256, 256, 0, stream>>>(acc2, dis, b2, batch,
                                                                pooled, counts, N);
    k_head<<<((long long)G * 64 + 255) / 256, 256, 0, stream>>>(pooled, counts, fcw, fcb,
                                                                (float*)d_out, G);
}

// Round 2
// 663.008 us; speedup vs baseline: 1.8111x; 1.8111x over previous
//
#include <hip/hip_runtime.h>
#include <math.h>

typedef short short8 __attribute__((ext_vector_type(8)));
typedef float f32x4 __attribute__((ext_vector_type(4)));

__device__ __forceinline__ short f2bf(float x) {
    unsigned u = __float_as_uint(x);
    u += 0x7fffu + ((u >> 16) & 1u);
    return (short)(u >> 16);
}

// ---------------------------------------------------------------------------
// K1: in-degree histogram (real edges only; self-loop added as +1 in k_dis)
__global__ void k_deg(const int* __restrict__ dst, int* __restrict__ degi, int E) {
    int i = blockIdx.x * 256 + threadIdx.x;
    if (i < E) atomicAdd(&degi[dst[i]], 1);
}

// K2: dis = rsqrt(deg), deg = in-degree + 1 (self loop), always >= 1
__global__ void k_dis(const int* __restrict__ degi, float* __restrict__ dis, int n) {
    int i = blockIdx.x * 256 + threadIdx.x;
    if (i < n) dis[i] = rsqrtf((float)(degi[i] + 1));
}

// K3: T1T[f][c] = bf16( sum_k emb[c][k] * W1[k][f] )   (transposed for MFMA B)
__global__ void k_t1t(const float* __restrict__ emb, const float* __restrict__ W1,
                      short* __restrict__ T1T) {
    int id = blockIdx.x * 256 + threadIdx.x;   // 0..16383
    int f = id >> 7, c = id & 127;
    float acc = 0.f;
#pragma unroll
    for (int k = 0; k < 64; ++k) acc += emb[c * 64 + k] * W1[k * 128 + f];
    T1T[id] = f2bf(acc);
}

// K3b: W2T[f][k] = bf16(W2[k][f])   [64 x 128] transposed for MFMA B
__global__ void k_w2t(const float* __restrict__ W2, short* __restrict__ W2T) {
    int id = blockIdx.x * 256 + threadIdx.x;   // 0..8191
    if (id >= 64 * 128) return;
    int f = id >> 7, k = id & 127;
    W2T[id] = f2bf(W2[k * 64 + f]);
}

// K4: per-dst vocab-weight accumulation.
//   w[dst][nid[src]] += dis[src]  for every edge (incl. self loops for i>=E)
__global__ void k_wacc(const int* __restrict__ src, const int* __restrict__ dst,
                       const int* __restrict__ nid, const float* __restrict__ dis,
                       float* __restrict__ w, int E, int n) {
    int i = blockIdx.x * 256 + threadIdx.x;
    if (i < E) {
        int s = src[i], d = dst[i];
        atomicAdd(&w[(size_t)d * 128 + nid[s]], dis[s]);
    } else if (i < E + n) {
        int v = i - E;
        atomicAdd(&w[(size_t)v * 128 + nid[v]], dis[v]);
    }
}

// K5: out1 = relu( dis[v] * (w[v] @ T1) + b1 )  via MFMA, one wave per 16 nodes.
// A = w (f32 -> bf16 in-register), B = T1T (bf16, [feature][k] so loads are
// contiguous in k). D layout: col = lane&15 (feature), row = (lane>>4)*4+r (node).
__global__ __launch_bounds__(256) void k_l1_mfma(
        const float* __restrict__ w, const short* __restrict__ T1T,
        const float* __restrict__ dis, const float* __restrict__ b1,
        float* __restrict__ out1, int nwaves) {
    int wave = (blockIdx.x * 256 + threadIdx.x) >> 6;
    int lane = threadIdx.x & 63;
    if (wave >= nwaves) return;
    int m = lane & 15;      // A row (node) on input side; D col (feature)
    int g4 = lane >> 4;     // k-group
    int nodeb = wave * 16;

    // A fragments: w[nodeb+m][g4*8 + i + 32*s], i=0..7
    short8 a[4];
    const float* wrow = w + (size_t)(nodeb + m) * 128 + g4 * 8;
#pragma unroll
    for (int s = 0; s < 4; ++s) {
        float av[8];
        *(f32x4*)(av)     = *(const f32x4*)(wrow + s * 32);
        *(f32x4*)(av + 4) = *(const f32x4*)(wrow + s * 32 + 4);
        short8 f;
#pragma unroll
        for (int i = 0; i < 8; ++i) f[i] = f2bf(av[i]);
        a[s] = f;
    }
    float dvals[4];
#pragma unroll
    for (int r = 0; r < 4; ++r) dvals[r] = dis[nodeb + g4 * 4 + r];

#pragma unroll
    for (int nt = 0; nt < 8; ++nt) {
        f32x4 acc = {0.f, 0.f, 0.f, 0.f};
        const short8* bp = (const short8*)(T1T + ((size_t)(nt * 16 + m) * 128 + g4 * 8));
#pragma unroll
        for (int s = 0; s < 4; ++s)
            acc = __builtin_amdgcn_mfma_f32_16x16x32_bf16(a[s], bp[s * 4], acc, 0, 0, 0);
        int col = nt * 16 + m;
        float bb = b1[col];
#pragma unroll
        for (int r = 0; r < 4; ++r) {
            int row = g4 * 4 + r;
            out1[(size_t)(nodeb + row) * 128 + col] = fmaxf(dvals[r] * acc[r] + bb, 0.f);
        }
    }
}

// K6: g[v] = dis[v] * (out1[v] @ W2)  via MFMA; acc2 init = g (self loop term)
__global__ __launch_bounds__(256) void k_l2_mfma(
        const float* __restrict__ out1, const short* __restrict__ W2T,
        const float* __restrict__ dis,
        float* __restrict__ g, float* __restrict__ acc2, int nwaves) {
    int wave = (blockIdx.x * 256 + threadIdx.x) >> 6;
    int lane = threadIdx.x & 63;
    if (wave >= nwaves) return;
    int m = lane & 15;
    int g4 = lane >> 4;
    int nodeb = wave * 16;

    short8 a[4];
    const float* xrow = out1 + (size_t)(nodeb + m) * 128 + g4 * 8;
#pragma unroll
    for (int s = 0; s < 4; ++s) {
        float av[8];
        *(f32x4*)(av)     = *(const f32x4*)(xrow + s * 32);
        *(f32x4*)(av + 4) = *(const f32x4*)(xrow + s * 32 + 4);
        short8 f;
#pragma unroll
        for (int i = 0; i < 8; ++i) f[i] = f2bf(av[i]);
        a[s] = f;
    }
    float dvals[4];
#pragma unroll
    for (int r = 0; r < 4; ++r) dvals[r] = dis[nodeb + g4 * 4 + r];

#pragma unroll
    for (int nt = 0; nt < 4; ++nt) {
        f32x4 acc = {0.f, 0.f, 0.f, 0.f};
        const short8* bp = (const short8*)(W2T + ((size_t)(nt * 16 + m) * 128 + g4 * 8));
#pragma unroll
        for (int s = 0; s < 4; ++s)
            acc = __builtin_amdgcn_mfma_f32_16x16x32_bf16(a[s], bp[s * 4], acc, 0, 0, 0);
        int col = nt * 16 + m;
#pragma unroll
        for (int r = 0; r < 4; ++r) {
            int row = g4 * 4 + r;
            float val = dvals[r] * acc[r];
            g[(size_t)(nodeb + row) * 64 + col]    = val;
            acc2[(size_t)(nodeb + row) * 64 + col] = val;
        }
    }
}

// K7: edge scatter for layer 2: acc2[dst] += g[src]   (one wave per edge)
__global__ void k_agg2(const int* __restrict__ src, const int* __restrict__ dst,
                       const float* __restrict__ g, float* __restrict__ acc2, int E) {
    int wg = (blockIdx.x * 256 + threadIdx.x) >> 6;
    int lane = threadIdx.x & 63;
    if (wg >= E) return;
    int s = src[wg], d = dst[wg];
    atomicAdd(&acc2[(size_t)d * 64 + lane], g[(size_t)s * 64 + lane]);
}

// K8: x2 = relu(dis*acc2 + b2); pool into per-graph sums + counts
__global__ void k_pool(const float* __restrict__ acc2, const float* __restrict__ dis,
                       const float* __restrict__ b2, const int* __restrict__ batch,
                       float* __restrict__ pooled, float* __restrict__ counts, int n) {
    int v = (blockIdx.x * 256 + threadIdx.x) >> 6;
    int lane = threadIdx.x & 63;
    if (v >= n) return;
    float x = fmaxf(dis[v] * acc2[(size_t)v * 64 + lane] + b2[lane], 0.f);
    int b = batch[v];
    atomicAdd(&pooled[(size_t)b * 64 + lane], x);
    if (lane == 0) atomicAdd(&counts[b], 1.0f);
}

// K9: mean pool + fc + sigmoid  (one wave per graph)
__global__ void k_head(const float* __restrict__ pooled, const float* __restrict__ counts,
                       const float* __restrict__ fc_w, const float* __restrict__ fc_b,
                       float* __restrict__ out, int ngraphs) {
    int gi = (blockIdx.x * 256 + threadIdx.x) >> 6;
    int lane = threadIdx.x & 63;
    if (gi >= ngraphs) return;
    float c = fmaxf(counts[gi], 1.0f);
    float a = (pooled[(size_t)gi * 64 + lane] / c) * fc_w[lane];
#pragma unroll
    for (int off = 32; off >= 1; off >>= 1) a += __shfl_down(a, off);
    if (lane == 0) out[gi] = 1.0f / (1.0f + expf(-(a + fc_b[0])));
}

extern "C" void kernel_launch(void* const* d_in, const int* in_sizes, int n_in,
                              void* d_out, int out_size, void* d_ws, size_t ws_size,
                              hipStream_t stream) {
    const int*   nid   = (const int*)d_in[0];
    const int*   eidx  = (const int*)d_in[1];
    const int*   batch = (const int*)d_in[2];
    const float* emb   = (const float*)d_in[3];
    const float* W1    = (const float*)d_in[4];
    const float* b1    = (const float*)d_in[5];
    const float* W2    = (const float*)d_in[6];
    const float* b2    = (const float*)d_in[7];
    const float* fcw   = (const float*)d_in[8];
    const float* fcb   = (const float*)d_in[9];

    const int N = in_sizes[0];
    const int E = in_sizes[1] / 2;
    const int G = out_size;
    const int* src = eidx;
    const int* dst = eidx + E;

    // workspace carve-out (256B aligned)
    char* p = (char*)d_ws;
    auto alloc = [&](size_t bytes) {
        char* r = p;
        p += (bytes + 255) & ~(size_t)255;
        return r;
    };
    int*   degi   = (int*)  alloc((size_t)N * 4);
    float* dis    = (float*)alloc((size_t)N * 4);
    short* T1T    = (short*)alloc(128 * 128 * 2);
    short* W2T    = (short*)alloc(64 * 128 * 2);
    float* w      = (float*)alloc((size_t)N * 128 * 4);
    float* out1   = (float*)alloc((size_t)N * 128 * 4);
    float* acc2   = (float*)alloc((size_t)N * 64 * 4);
    float* pooled = (float*)alloc((size_t)G * 64 * 4);
    float* counts = (float*)alloc((size_t)G * 4);
    float* g = w;  // alias: w dead after k_l1_mfma; g written in k_l2_mfma

    hipMemsetAsync(degi, 0, (size_t)N * 4, stream);
    hipMemsetAsync(w, 0, (size_t)N * 128 * 4, stream);
    hipMemsetAsync(pooled, 0, (size_t)G * 64 * 4, stream);
    hipMemsetAsync(counts, 0, (size_t)G * 4, stream);

    k_deg<<<(E + 255) / 256, 256, 0, stream>>>(dst, degi, E);
    k_dis<<<(N + 255) / 256, 256, 0, stream>>>(degi, dis, N);
    k_t1t<<<64, 256, 0, stream>>>(emb, W1, T1T);
    k_w2t<<<32, 256, 0, stream>>>(W2, W2T);
    k_wacc<<<(E + N + 255) / 256, 256, 0, stream>>>(src, dst, nid, dis, w, E, N);

    int nwaves = (N + 15) / 16;                 // N=100000 -> 6250, exact
    int nblk = (nwaves + 3) / 4;
    k_l1_mfma<<<nblk, 256, 0, stream>>>(w, T1T, dis, b1, out1, nwaves);
    k_l2_mfma<<<nblk, 256, 0, stream>>>(out1, W2T, dis, g, acc2, nwaves);
    {
        long long waves = (long long)E;
        long long blocks = (waves * 64 + 255) / 256;
        k_agg2<<<(int)blocks, 256, 0, stream>>>(src, dst, g, acc2, E);
    }
    k_pool<<<((long long)N * 64 + 255) / 256, 256, 0, stream>>>(acc2, dis, b2, batch,
                                                                pooled, counts, N);
    k_head<<<((long long)G * 64 + 255) / 256, 256, 0, stream>>>(pooled, counts, fcw, fcb,
                                                                (float*)d_out, G);
}

// Round 3
// 520.498 us; speedup vs baseline: 2.3069x; 1.2738x over previous
//
#include <hip/hip_runtime.h>
#include <math.h>

typedef short short8 __attribute__((ext_vector_type(8)));
typedef float f32x4 __attribute__((ext_vector_type(4)));

__device__ __forceinline__ short f2bf(float x) {
    unsigned u = __float_as_uint(x);
    u += 0x7fffu + ((u >> 16) & 1u);
    return (short)(u >> 16);
}

// ---------------------------------------------------------------------------
// K1: in-degree histogram (real edges only; self-loop added as +1 in k_dis)
__global__ void k_deg(const int* __restrict__ dst, int* __restrict__ degi, int E) {
    int i = blockIdx.x * 256 + threadIdx.x;
    if (i < E) atomicAdd(&degi[dst[i]], 1);
}

// K2: dis = rsqrt(deg), deg = in-degree + 1 (self loop), always >= 1
__global__ void k_dis(const int* __restrict__ degi, float* __restrict__ dis, int n) {
    int i = blockIdx.x * 256 + threadIdx.x;
    if (i < n) dis[i] = rsqrtf((float)(degi[i] + 1));
}

// ---------------------------------------------------------------------------
// CSR build: exclusive scan of degi -> rowptr, then cursor-scatter src ids.
// scan_a: per-chunk (1024 elems) exclusive scan + chunk totals
__global__ void k_scan_a(const int* __restrict__ degi, int* __restrict__ rowptr,
                         int* __restrict__ csums, int n) {
    __shared__ int sdata[256];
    int tid = threadIdx.x;
    int idx = blockIdx.x * 1024 + tid * 4;
    int v[4];
#pragma unroll
    for (int j = 0; j < 4; ++j) v[j] = (idx + j < n) ? degi[idx + j] : 0;
    int tsum = v[0] + v[1] + v[2] + v[3];
    sdata[tid] = tsum;
    __syncthreads();
    for (int off = 1; off < 256; off <<= 1) {
        int add = (tid >= off) ? sdata[tid - off] : 0;
        __syncthreads();
        sdata[tid] += add;
        __syncthreads();
    }
    int excl = sdata[tid] - tsum;   // exclusive offset of this thread within chunk
    int run = 0;
#pragma unroll
    for (int j = 0; j < 4; ++j) {
        if (idx + j < n) rowptr[idx + j] = excl + run;
        run += v[j];
    }
    if (tid == 255) csums[blockIdx.x] = sdata[255];
}

// scan_b: single block exclusive scan of csums[nch] (nch <= 1024)
__global__ void k_scan_b(int* __restrict__ csums, int nch) {
    __shared__ int sdata[256];
    int tid = threadIdx.x;
    int v[4];
#pragma unroll
    for (int j = 0; j < 4; ++j) {
        int i = tid * 4 + j;
        v[j] = (i < nch) ? csums[i] : 0;
    }
    int tsum = v[0] + v[1] + v[2] + v[3];
    sdata[tid] = tsum;
    __syncthreads();
    for (int off = 1; off < 256; off <<= 1) {
        int add = (tid >= off) ? sdata[tid - off] : 0;
        __syncthreads();
        sdata[tid] += add;
        __syncthreads();
    }
    int excl = sdata[tid] - tsum;
    int run = 0;
#pragma unroll
    for (int j = 0; j < 4; ++j) {
        int i = tid * 4 + j;
        if (i < nch) csums[i] = excl + run;
        run += v[j];
    }
}

// scan_c: add chunk offsets; copy rowptr -> cur; set rowptr[n] = E
__global__ void k_scan_c(int* __restrict__ rowptr, int* __restrict__ cur,
                         const int* __restrict__ csums, int n, int E) {
    int idx = blockIdx.x * 1024 + threadIdx.x * 4;
    int add = csums[blockIdx.x];
#pragma unroll
    for (int j = 0; j < 4; ++j) {
        if (idx + j < n) {
            int r = rowptr[idx + j] + add;
            rowptr[idx + j] = r;
            cur[idx + j] = r;
        }
    }
    if (blockIdx.x == 0 && threadIdx.x == 0) rowptr[n] = E;
}

// fill: esrc[pos] = src for each edge, bucketed by dst
__global__ void k_fill(const int* __restrict__ src, const int* __restrict__ dst,
                       int* __restrict__ cur, int* __restrict__ esrc, int E) {
    int i = blockIdx.x * 256 + threadIdx.x;
    if (i >= E) return;
    int d = dst[i];
    int pos = atomicAdd(&cur[d], 1);
    esrc[pos] = src[i];
}

// ---------------------------------------------------------------------------
// K3: T1T[f][c] = bf16( sum_k emb[c][k] * W1[k][f] )   (transposed for MFMA B)
__global__ void k_t1t(const float* __restrict__ emb, const float* __restrict__ W1,
                      short* __restrict__ T1T) {
    int id = blockIdx.x * 256 + threadIdx.x;   // 0..16383
    int f = id >> 7, c = id & 127;
    float acc = 0.f;
#pragma unroll
    for (int k = 0; k < 64; ++k) acc += emb[c * 64 + k] * W1[k * 128 + f];
    T1T[id] = f2bf(acc);
}

// K3b: W2T[f][k] = bf16(W2[k][f])   [64 x 128] transposed for MFMA B
__global__ void k_w2t(const float* __restrict__ W2, short* __restrict__ W2T) {
    int id = blockIdx.x * 256 + threadIdx.x;   // 0..8191
    if (id >= 64 * 128) return;
    int f = id >> 7, k = id & 127;
    W2T[id] = f2bf(W2[k * 64 + f]);
}

// K4: per-dst vocab-weight accumulation.
//   w[dst][nid[src]] += dis[src]  for every edge (incl. self loops for i>=E)
__global__ void k_wacc(const int* __restrict__ src, const int* __restrict__ dst,
                       const int* __restrict__ nid, const float* __restrict__ dis,
                       float* __restrict__ w, int E, int n) {
    int i = blockIdx.x * 256 + threadIdx.x;
    if (i < E) {
        int s = src[i], d = dst[i];
        atomicAdd(&w[(size_t)d * 128 + nid[s]], dis[s]);
    } else if (i < E + n) {
        int v = i - E;
        atomicAdd(&w[(size_t)v * 128 + nid[v]], dis[v]);
    }
}

// K5: out1 = relu( dis[v] * (w[v] @ T1) + b1 )  via MFMA, one wave per 16 nodes.
__global__ __launch_bounds__(256) void k_l1_mfma(
        const float* __restrict__ w, const short* __restrict__ T1T,
        const float* __restrict__ dis, const float* __restrict__ b1,
        float* __restrict__ out1, int nwaves) {
    int wave = (blockIdx.x * 256 + threadIdx.x) >> 6;
    int lane = threadIdx.x & 63;
    if (wave >= nwaves) return;
    int m = lane & 15;      // A row (node); D col (feature)
    int g4 = lane >> 4;     // k-group
    int nodeb = wave * 16;

    short8 a[4];
    const float* wrow = w + (size_t)(nodeb + m) * 128 + g4 * 8;
#pragma unroll
    for (int s = 0; s < 4; ++s) {
        float av[8];
        *(f32x4*)(av)     = *(const f32x4*)(wrow + s * 32);
        *(f32x4*)(av + 4) = *(const f32x4*)(wrow + s * 32 + 4);
        short8 f;
#pragma unroll
        for (int i = 0; i < 8; ++i) f[i] = f2bf(av[i]);
        a[s] = f;
    }
    float dvals[4];
#pragma unroll
    for (int r = 0; r < 4; ++r) dvals[r] = dis[nodeb + g4 * 4 + r];

#pragma unroll
    for (int nt = 0; nt < 8; ++nt) {
        f32x4 acc = {0.f, 0.f, 0.f, 0.f};
        const short8* bp = (const short8*)(T1T + ((size_t)(nt * 16 + m) * 128 + g4 * 8));
#pragma unroll
        for (int s = 0; s < 4; ++s)
            acc = __builtin_amdgcn_mfma_f32_16x16x32_bf16(a[s], bp[s * 4], acc, 0, 0, 0);
        int col = nt * 16 + m;
        float bb = b1[col];
#pragma unroll
        for (int r = 0; r < 4; ++r) {
            int row = g4 * 4 + r;
            out1[(size_t)(nodeb + row) * 128 + col] = fmaxf(dvals[r] * acc[r] + bb, 0.f);
        }
    }
}

// K6: g[v] = dis[v] * (out1[v] @ W2)  via MFMA (self-loop term added in gather)
__global__ __launch_bounds__(256) void k_l2_mfma(
        const float* __restrict__ out1, const short* __restrict__ W2T,
        const float* __restrict__ dis,
        float* __restrict__ g, int nwaves) {
    int wave = (blockIdx.x * 256 + threadIdx.x) >> 6;
    int lane = threadIdx.x & 63;
    if (wave >= nwaves) return;
    int m = lane & 15;
    int g4 = lane >> 4;
    int nodeb = wave * 16;

    short8 a[4];
    const float* xrow = out1 + (size_t)(nodeb + m) * 128 + g4 * 8;
#pragma unroll
    for (int s = 0; s < 4; ++s) {
        float av[8];
        *(f32x4*)(av)     = *(const f32x4*)(xrow + s * 32);
        *(f32x4*)(av + 4) = *(const f32x4*)(xrow + s * 32 + 4);
        short8 f;
#pragma unroll
        for (int i = 0; i < 8; ++i) f[i] = f2bf(av[i]);
        a[s] = f;
    }
    float dvals[4];
#pragma unroll
    for (int r = 0; r < 4; ++r) dvals[r] = dis[nodeb + g4 * 4 + r];

#pragma unroll
    for (int nt = 0; nt < 4; ++nt) {
        f32x4 acc = {0.f, 0.f, 0.f, 0.f};
        const short8* bp = (const short8*)(W2T + ((size_t)(nt * 16 + m) * 128 + g4 * 8));
#pragma unroll
        for (int s = 0; s < 4; ++s)
            acc = __builtin_amdgcn_mfma_f32_16x16x32_bf16(a[s], bp[s * 4], acc, 0, 0, 0);
        int col = nt * 16 + m;
#pragma unroll
        for (int r = 0; r < 4; ++r) {
            int row = g4 * 4 + r;
            g[(size_t)(nodeb + row) * 64 + col] = dvals[r] * acc[r];
        }
    }
}

// K7: gather + relu + pool. One wave per dst node; lane = feature.
__global__ void k_gather_pool(const int* __restrict__ rowptr, const int* __restrict__ esrc,
                              const float* __restrict__ g, const float* __restrict__ dis,
                              const float* __restrict__ b2, const int* __restrict__ batch,
                              float* __restrict__ pooled, float* __restrict__ counts,
                              int n) {
    int v = (blockIdx.x * 256 + threadIdx.x) >> 6;
    int lane = threadIdx.x & 63;
    if (v >= n) return;
    int e = rowptr[v], re = rowptr[v + 1];
    float a0 = g[(size_t)v * 64 + lane];     // self loop
    float a1 = 0.f, a2 = 0.f, a3 = 0.f;
    for (; e + 4 <= re; e += 4) {
        int s0 = esrc[e], s1 = esrc[e + 1], s2 = esrc[e + 2], s3 = esrc[e + 3];
        a0 += g[(size_t)s0 * 64 + lane];
        a1 += g[(size_t)s1 * 64 + lane];
        a2 += g[(size_t)s2 * 64 + lane];
        a3 += g[(size_t)s3 * 64 + lane];
    }
    for (; e < re; ++e) a0 += g[(size_t)esrc[e] * 64 + lane];
    float acc = (a0 + a1) + (a2 + a3);
    float x = fmaxf(dis[v] * acc + b2[lane], 0.f);
    int b = batch[v];
    atomicAdd(&pooled[(size_t)b * 64 + lane], x);
    if (lane == 0) atomicAdd(&counts[b], 1.0f);
}

// K8: mean pool + fc + sigmoid  (one wave per graph)
__global__ void k_head(const float* __restrict__ pooled, const float* __restrict__ counts,
                       const float* __restrict__ fc_w, const float* __restrict__ fc_b,
                       float* __restrict__ out, int ngraphs) {
    int gi = (blockIdx.x * 256 + threadIdx.x) >> 6;
    int lane = threadIdx.x & 63;
    if (gi >= ngraphs) return;
    float c = fmaxf(counts[gi], 1.0f);
    float a = (pooled[(size_t)gi * 64 + lane] / c) * fc_w[lane];
#pragma unroll
    for (int off = 32; off >= 1; off >>= 1) a += __shfl_down(a, off);
    if (lane == 0) out[gi] = 1.0f / (1.0f + expf(-(a + fc_b[0])));
}

extern "C" void kernel_launch(void* const* d_in, const int* in_sizes, int n_in,
                              void* d_out, int out_size, void* d_ws, size_t ws_size,
                              hipStream_t stream) {
    const int*   nid   = (const int*)d_in[0];
    const int*   eidx  = (const int*)d_in[1];
    const int*   batch = (const int*)d_in[2];
    const float* emb   = (const float*)d_in[3];
    const float* W1    = (const float*)d_in[4];
    const float* b1    = (const float*)d_in[5];
    const float* W2    = (const float*)d_in[6];
    const float* b2    = (const float*)d_in[7];
    const float* fcw   = (const float*)d_in[8];
    const float* fcb   = (const float*)d_in[9];

    const int N = in_sizes[0];
    const int E = in_sizes[1] / 2;
    const int G = out_size;
    const int* src = eidx;
    const int* dst = eidx + E;

    // workspace carve-out (256B aligned)
    char* p = (char*)d_ws;
    auto alloc = [&](size_t bytes) {
        char* r = p;
        p += (bytes + 255) & ~(size_t)255;
        return r;
    };
    int*   degi   = (int*)  alloc((size_t)N * 4);
    float* dis    = (float*)alloc((size_t)N * 4);
    short* T1T    = (short*)alloc(128 * 128 * 2);
    short* W2T    = (short*)alloc(64 * 128 * 2);
    float* w      = (float*)alloc((size_t)N * 128 * 4);
    float* out1   = (float*)alloc((size_t)N * 128 * 4);
    int*   rowptr = (int*)  alloc((size_t)(N + 1) * 4);
    int*   cur    = (int*)  alloc((size_t)N * 4);
    int*   csums  = (int*)  alloc(4096 * 4);
    int*   esrc   = (int*)  alloc((size_t)E * 4);
    float* pooled = (float*)alloc((size_t)G * 64 * 4);
    float* counts = (float*)alloc((size_t)G * 4);
    float* g = w;  // alias: w dead after k_l1_mfma; g written in k_l2_mfma

    hipMemsetAsync(degi, 0, (size_t)N * 4, stream);
    hipMemsetAsync(w, 0, (size_t)N * 128 * 4, stream);
    hipMemsetAsync(pooled, 0, (size_t)G * 64 * 4, stream);
    hipMemsetAsync(counts, 0, (size_t)G * 4, stream);

    k_deg<<<(E + 255) / 256, 256, 0, stream>>>(dst, degi, E);
    k_dis<<<(N + 255) / 256, 256, 0, stream>>>(degi, dis, N);

    // CSR build
    int nch = (N + 1023) / 1024;
    k_scan_a<<<nch, 256, 0, stream>>>(degi, rowptr, csums, N);
    k_scan_b<<<1, 256, 0, stream>>>(csums, nch);
    k_scan_c<<<nch, 256, 0, stream>>>(rowptr, cur, csums, N, E);
    k_fill<<<(E + 255) / 256, 256, 0, stream>>>(src, dst, cur, esrc, E);

    k_t1t<<<64, 256, 0, stream>>>(emb, W1, T1T);
    k_w2t<<<32, 256, 0, stream>>>(W2, W2T);
    k_wacc<<<(E + N + 255) / 256, 256, 0, stream>>>(src, dst, nid, dis, w, E, N);

    int nwaves = (N + 15) / 16;                 // N=100000 -> 6250, exact
    int nblk = (nwaves + 3) / 4;
    k_l1_mfma<<<nblk, 256, 0, stream>>>(w, T1T, dis, b1, out1, nwaves);
    k_l2_mfma<<<nblk, 256, 0, stream>>>(out1, W2T, dis, g, nwaves);

    k_gather_pool<<<((long long)N * 64 + 255) / 256, 256, 0, stream>>>(
        rowptr, esrc, g, dis, b2, batch, pooled, counts, N);
    k_head<<<((long long)G * 64 + 255) / 256, 256, 0, stream>>>(pooled, counts, fcw, fcb,
                                                                (float*)d_out, G);
}

// Round 4
// 497.572 us; speedup vs baseline: 2.4132x; 1.0461x over previous
//
#include <hip/hip_runtime.h>
#include <math.h>

typedef short short8 __attribute__((ext_vector_type(8)));
typedef float f32x4 __attribute__((ext_vector_type(4)));

__device__ __forceinline__ short f2bf(float x) {
    unsigned u = __float_as_uint(x);
    u += 0x7fffu + ((u >> 16) & 1u);
    return (short)(u >> 16);
}
__device__ __forceinline__ float bf2f(unsigned short u) {
    return __uint_as_float(((unsigned)u) << 16);
}

// ---------------------------------------------------------------------------
// K1: in-degree histogram (real edges only; self-loop added as +1 in k_dis)
__global__ void k_deg(const int* __restrict__ dst, int* __restrict__ degi, int E) {
    int i = blockIdx.x * 256 + threadIdx.x;
    if (i < E) atomicAdd(&degi[dst[i]], 1);
}

// K2: dis = rsqrt(deg), deg = in-degree + 1 (self loop), always >= 1
__global__ void k_dis(const int* __restrict__ degi, float* __restrict__ dis, int n) {
    int i = blockIdx.x * 256 + threadIdx.x;
    if (i < n) dis[i] = rsqrtf((float)(degi[i] + 1));
}

// ---------------------------------------------------------------------------
// CSR build: exclusive scan of degi -> rowptr, then cursor-scatter src ids.
__global__ void k_scan_a(const int* __restrict__ degi, int* __restrict__ rowptr,
                         int* __restrict__ csums, int n) {
    __shared__ int sdata[256];
    int tid = threadIdx.x;
    int idx = blockIdx.x * 1024 + tid * 4;
    int v[4];
#pragma unroll
    for (int j = 0; j < 4; ++j) v[j] = (idx + j < n) ? degi[idx + j] : 0;
    int tsum = v[0] + v[1] + v[2] + v[3];
    sdata[tid] = tsum;
    __syncthreads();
    for (int off = 1; off < 256; off <<= 1) {
        int add = (tid >= off) ? sdata[tid - off] : 0;
        __syncthreads();
        sdata[tid] += add;
        __syncthreads();
    }
    int excl = sdata[tid] - tsum;
    int run = 0;
#pragma unroll
    for (int j = 0; j < 4; ++j) {
        if (idx + j < n) rowptr[idx + j] = excl + run;
        run += v[j];
    }
    if (tid == 255) csums[blockIdx.x] = sdata[255];
}

__global__ void k_scan_b(int* __restrict__ csums, int nch) {
    __shared__ int sdata[256];
    int tid = threadIdx.x;
    int v[4];
#pragma unroll
    for (int j = 0; j < 4; ++j) {
        int i = tid * 4 + j;
        v[j] = (i < nch) ? csums[i] : 0;
    }
    int tsum = v[0] + v[1] + v[2] + v[3];
    sdata[tid] = tsum;
    __syncthreads();
    for (int off = 1; off < 256; off <<= 1) {
        int add = (tid >= off) ? sdata[tid - off] : 0;
        __syncthreads();
        sdata[tid] += add;
        __syncthreads();
    }
    int excl = sdata[tid] - tsum;
    int run = 0;
#pragma unroll
    for (int j = 0; j < 4; ++j) {
        int i = tid * 4 + j;
        if (i < nch) csums[i] = excl + run;
        run += v[j];
    }
}

__global__ void k_scan_c(int* __restrict__ rowptr, int* __restrict__ cur,
                         const int* __restrict__ csums, int n, int E) {
    int idx = blockIdx.x * 1024 + threadIdx.x * 4;
    int add = csums[blockIdx.x];
#pragma unroll
    for (int j = 0; j < 4; ++j) {
        if (idx + j < n) {
            int r = rowptr[idx + j] + add;
            rowptr[idx + j] = r;
            cur[idx + j] = r;
        }
    }
    if (blockIdx.x == 0 && threadIdx.x == 0) rowptr[n] = E;
}

__global__ void k_fill(const int* __restrict__ src, const int* __restrict__ dst,
                       int* __restrict__ cur, int* __restrict__ esrc, int E) {
    int i = blockIdx.x * 256 + threadIdx.x;
    if (i >= E) return;
    int d = dst[i];
    int pos = atomicAdd(&cur[d], 1);
    esrc[pos] = src[i];
}

// ---------------------------------------------------------------------------
// K3: T1T[f][c] = bf16( sum_k emb[c][k] * W1[k][f] )   (transposed for MFMA B)
__global__ void k_t1t(const float* __restrict__ emb, const float* __restrict__ W1,
                      short* __restrict__ T1T) {
    int id = blockIdx.x * 256 + threadIdx.x;   // 0..16383
    int f = id >> 7, c = id & 127;
    float acc = 0.f;
#pragma unroll
    for (int k = 0; k < 64; ++k) acc += emb[c * 64 + k] * W1[k * 128 + f];
    T1T[id] = f2bf(acc);
}

// K3b: W2T[f][k] = bf16(W2[k][f])   [64 x 128] transposed for MFMA B
__global__ void k_w2t(const float* __restrict__ W2, short* __restrict__ W2T) {
    int id = blockIdx.x * 256 + threadIdx.x;   // 0..8191
    if (id >= 64 * 128) return;
    int f = id >> 7, k = id & 127;
    W2T[id] = f2bf(W2[k * 64 + f]);
}

// K4: per-dst vocab-weight accumulation.
__global__ void k_wacc(const int* __restrict__ src, const int* __restrict__ dst,
                       const int* __restrict__ nid, const float* __restrict__ dis,
                       float* __restrict__ w, int E, int n) {
    int i = blockIdx.x * 256 + threadIdx.x;
    if (i < E) {
        int s = src[i], d = dst[i];
        atomicAdd(&w[(size_t)d * 128 + nid[s]], dis[s]);
    } else if (i < E + n) {
        int v = i - E;
        atomicAdd(&w[(size_t)v * 128 + nid[v]], dis[v]);
    }
}

// K5: out1 = relu( dis[v] * (w[v] @ T1) + b1 )  via MFMA, one wave per 16 nodes.
__global__ __launch_bounds__(256) void k_l1_mfma(
        const float* __restrict__ w, const short* __restrict__ T1T,
        const float* __restrict__ dis, const float* __restrict__ b1,
        float* __restrict__ out1, int nwaves) {
    int wave = (blockIdx.x * 256 + threadIdx.x) >> 6;
    int lane = threadIdx.x & 63;
    if (wave >= nwaves) return;
    int m = lane & 15;      // A row (node); D col (feature)
    int g4 = lane >> 4;     // k-group
    int nodeb = wave * 16;

    short8 a[4];
    const float* wrow = w + (size_t)(nodeb + m) * 128 + g4 * 8;
#pragma unroll
    for (int s = 0; s < 4; ++s) {
        float av[8];
        *(f32x4*)(av)     = *(const f32x4*)(wrow + s * 32);
        *(f32x4*)(av + 4) = *(const f32x4*)(wrow + s * 32 + 4);
        short8 f;
#pragma unroll
        for (int i = 0; i < 8; ++i) f[i] = f2bf(av[i]);
        a[s] = f;
    }
    float dvals[4];
#pragma unroll
    for (int r = 0; r < 4; ++r) dvals[r] = dis[nodeb + g4 * 4 + r];

#pragma unroll
    for (int nt = 0; nt < 8; ++nt) {
        f32x4 acc = {0.f, 0.f, 0.f, 0.f};
        const short8* bp = (const short8*)(T1T + ((size_t)(nt * 16 + m) * 128 + g4 * 8));
#pragma unroll
        for (int s = 0; s < 4; ++s)
            acc = __builtin_amdgcn_mfma_f32_16x16x32_bf16(a[s], bp[s * 4], acc, 0, 0, 0);
        int col = nt * 16 + m;
        float bb = b1[col];
#pragma unroll
        for (int r = 0; r < 4; ++r) {
            int row = g4 * 4 + r;
            out1[(size_t)(nodeb + row) * 128 + col] = fmaxf(dvals[r] * acc[r] + bb, 0.f);
        }
    }
}

// K6: g[v] = bf16( dis[v] * (out1[v] @ W2) )  via MFMA (self-loop added in gather)
__global__ __launch_bounds__(256) void k_l2_mfma(
        const float* __restrict__ out1, const short* __restrict__ W2T,
        const float* __restrict__ dis,
        unsigned short* __restrict__ g, int nwaves) {
    int wave = (blockIdx.x * 256 + threadIdx.x) >> 6;
    int lane = threadIdx.x & 63;
    if (wave >= nwaves) return;
    int m = lane & 15;
    int g4 = lane >> 4;
    int nodeb = wave * 16;

    short8 a[4];
    const float* xrow = out1 + (size_t)(nodeb + m) * 128 + g4 * 8;
#pragma unroll
    for (int s = 0; s < 4; ++s) {
        float av[8];
        *(f32x4*)(av)     = *(const f32x4*)(xrow + s * 32);
        *(f32x4*)(av + 4) = *(const f32x4*)(xrow + s * 32 + 4);
        short8 f;
#pragma unroll
        for (int i = 0; i < 8; ++i) f[i] = f2bf(av[i]);
        a[s] = f;
    }
    float dvals[4];
#pragma unroll
    for (int r = 0; r < 4; ++r) dvals[r] = dis[nodeb + g4 * 4 + r];

#pragma unroll
    for (int nt = 0; nt < 4; ++nt) {
        f32x4 acc = {0.f, 0.f, 0.f, 0.f};
        const short8* bp = (const short8*)(W2T + ((size_t)(nt * 16 + m) * 128 + g4 * 8));
#pragma unroll
        for (int s = 0; s < 4; ++s)
            acc = __builtin_amdgcn_mfma_f32_16x16x32_bf16(a[s], bp[s * 4], acc, 0, 0, 0);
        int col = nt * 16 + m;
#pragma unroll
        for (int r = 0; r < 4; ++r) {
            int row = g4 * 4 + r;
            g[(size_t)(nodeb + row) * 64 + col] = (unsigned short)f2bf(dvals[r] * acc[r]);
        }
    }
}

// K7: gather(bf16) + relu + pool. One wave per dst node; lane = feature.
// 8 gathers in flight per wave; esrc loaded coalesced per-lane + shfl broadcast.
__global__ void k_gather_pool(const int* __restrict__ rowptr, const int* __restrict__ esrc,
                              const unsigned short* __restrict__ g,
                              const float* __restrict__ dis,
                              const float* __restrict__ b2, const int* __restrict__ batch,
                              float* __restrict__ pooled, float* __restrict__ counts,
                              int n) {
    int v = (blockIdx.x * 256 + threadIdx.x) >> 6;
    int lane = threadIdx.x & 63;
    if (v >= n) return;
    int e = rowptr[v], re = rowptr[v + 1];
    float a0 = bf2f(g[(size_t)v * 64 + lane]);   // self loop
    float a1 = 0.f, a2 = 0.f, a3 = 0.f, a4 = 0.f, a5 = 0.f, a6 = 0.f, a7 = 0.f;
    int l8 = lane & 7;
    for (; e + 8 <= re; e += 8) {
        int sl = esrc[e + l8];                    // coalesced; 8 distinct values/wave
        int s0 = __shfl(sl, 0, 8), s1 = __shfl(sl, 1, 8);
        int s2 = __shfl(sl, 2, 8), s3 = __shfl(sl, 3, 8);
        int s4 = __shfl(sl, 4, 8), s5 = __shfl(sl, 5, 8);
        int s6 = __shfl(sl, 6, 8), s7 = __shfl(sl, 7, 8);
        a0 += bf2f(g[(size_t)s0 * 64 + lane]);
        a1 += bf2f(g[(size_t)s1 * 64 + lane]);
        a2 += bf2f(g[(size_t)s2 * 64 + lane]);
        a3 += bf2f(g[(size_t)s3 * 64 + lane]);
        a4 += bf2f(g[(size_t)s4 * 64 + lane]);
        a5 += bf2f(g[(size_t)s5 * 64 + lane]);
        a6 += bf2f(g[(size_t)s6 * 64 + lane]);
        a7 += bf2f(g[(size_t)s7 * 64 + lane]);
    }
    for (; e < re; ++e) a0 += bf2f(g[(size_t)esrc[e] * 64 + lane]);
    float acc = ((a0 + a1) + (a2 + a3)) + ((a4 + a5) + (a6 + a7));
    float x = fmaxf(dis[v] * acc + b2[lane], 0.f);
    int b = batch[v];
    atomicAdd(&pooled[(size_t)b * 64 + lane], x);
    if (lane == 0) atomicAdd(&counts[b], 1.0f);
}

// K8: mean pool + fc + sigmoid  (one wave per graph)
__global__ void k_head(const float* __restrict__ pooled, const float* __restrict__ counts,
                       const float* __restrict__ fc_w, const float* __restrict__ fc_b,
                       float* __restrict__ out, int ngraphs) {
    int gi = (blockIdx.x * 256 + threadIdx.x) >> 6;
    int lane = threadIdx.x & 63;
    if (gi >= ngraphs) return;
    float c = fmaxf(counts[gi], 1.0f);
    float a = (pooled[(size_t)gi * 64 + lane] / c) * fc_w[lane];
#pragma unroll
    for (int off = 32; off >= 1; off >>= 1) a += __shfl_down(a, off);
    if (lane == 0) out[gi] = 1.0f / (1.0f + expf(-(a + fc_b[0])));
}

extern "C" void kernel_launch(void* const* d_in, const int* in_sizes, int n_in,
                              void* d_out, int out_size, void* d_ws, size_t ws_size,
                              hipStream_t stream) {
    const int*   nid   = (const int*)d_in[0];
    const int*   eidx  = (const int*)d_in[1];
    const int*   batch = (const int*)d_in[2];
    const float* emb   = (const float*)d_in[3];
    const float* W1    = (const float*)d_in[4];
    const float* b1    = (const float*)d_in[5];
    const float* W2    = (const float*)d_in[6];
    const float* b2    = (const float*)d_in[7];
    const float* fcw   = (const float*)d_in[8];
    const float* fcb   = (const float*)d_in[9];

    const int N = in_sizes[0];
    const int E = in_sizes[1] / 2;
    const int G = out_size;
    const int* src = eidx;
    const int* dst = eidx + E;

    // workspace carve-out (256B aligned)
    char* p = (char*)d_ws;
    auto alloc = [&](size_t bytes) {
        char* r = p;
        p += (bytes + 255) & ~(size_t)255;
        return r;
    };
    int*   degi   = (int*)  alloc((size_t)N * 4);
    float* dis    = (float*)alloc((size_t)N * 4);
    short* T1T    = (short*)alloc(128 * 128 * 2);
    short* W2T    = (short*)alloc(64 * 128 * 2);
    float* w      = (float*)alloc((size_t)N * 128 * 4);
    float* out1   = (float*)alloc((size_t)N * 128 * 4);
    int*   rowptr = (int*)  alloc((size_t)(N + 1) * 4);
    int*   cur    = (int*)  alloc((size_t)N * 4);
    int*   csums  = (int*)  alloc(4096 * 4);
    int*   esrc   = (int*)  alloc((size_t)E * 4);
    float* pooled = (float*)alloc((size_t)G * 64 * 4);
    float* counts = (float*)alloc((size_t)G * 4);
    unsigned short* g = (unsigned short*)w;  // alias: w dead after k_l1_mfma

    hipMemsetAsync(degi, 0, (size_t)N * 4, stream);
    hipMemsetAsync(w, 0, (size_t)N * 128 * 4, stream);
    hipMemsetAsync(pooled, 0, (size_t)G * 64 * 4, stream);
    hipMemsetAsync(counts, 0, (size_t)G * 4, stream);

    k_deg<<<(E + 255) / 256, 256, 0, stream>>>(dst, degi, E);
    k_dis<<<(N + 255) / 256, 256, 0, stream>>>(degi, dis, N);

    // CSR build
    int nch = (N + 1023) / 1024;
    k_scan_a<<<nch, 256, 0, stream>>>(degi, rowptr, csums, N);
    k_scan_b<<<1, 256, 0, stream>>>(csums, nch);
    k_scan_c<<<nch, 256, 0, stream>>>(rowptr, cur, csums, N, E);
    k_fill<<<(E + 255) / 256, 256, 0, stream>>>(src, dst, cur, esrc, E);

    k_t1t<<<64, 256, 0, stream>>>(emb, W1, T1T);
    k_w2t<<<32, 256, 0, stream>>>(W2, W2T);
    k_wacc<<<(E + N + 255) / 256, 256, 0, stream>>>(src, dst, nid, dis, w, E, N);

    int nwaves = (N + 15) / 16;                 // N=100000 -> 6250, exact
    int nblk = (nwaves + 3) / 4;
    k_l1_mfma<<<nblk, 256, 0, stream>>>(w, T1T, dis, b1, out1, nwaves);
    k_l2_mfma<<<nblk, 256, 0, stream>>>(out1, W2T, dis, g, nwaves);

    k_gather_pool<<<((long long)N * 64 + 255) / 256, 256, 0, stream>>>(
        rowptr, esrc, g, dis, b2, batch, pooled, counts, N);
    k_head<<<((long long)G * 64 + 255) / 256, 256, 0, stream>>>(pooled, counts, fcw, fcb,
                                                                (float*)d_out, G);
}

// Round 5
// 336.437 us; speedup vs baseline: 3.5690x; 1.4789x over previous
//
#include <hip/hip_runtime.h>
#include <math.h>

typedef short short8 __attribute__((ext_vector_type(8)));
typedef float f32x4 __attribute__((ext_vector_type(4)));

#define WP 132   // wtile pitch (f32)  : 16-row tile, 2-way-free bank pattern
#define OP 136   // otile pitch (bf16)

__device__ __forceinline__ short f2bf(float x) {
    unsigned u = __float_as_uint(x);
    u += 0x7fffu + ((u >> 16) & 1u);
    return (short)(u >> 16);
}
__device__ __forceinline__ float bf2f(unsigned short u) {
    return __uint_as_float(((unsigned)u) << 16);
}

// ---------------------------------------------------------------------------
// K1: in-degree histogram (real edges only; self-loop added as +1 in k_dis)
__global__ void k_deg(const int* __restrict__ dst, int* __restrict__ degi, int E) {
    int i = blockIdx.x * 256 + threadIdx.x;
    if (i < E) atomicAdd(&degi[dst[i]], 1);
}

// K2: dis = rsqrt(deg), deg = in-degree + 1 (self loop), always >= 1
__global__ void k_dis(const int* __restrict__ degi, float* __restrict__ dis, int n) {
    int i = blockIdx.x * 256 + threadIdx.x;
    if (i < n) dis[i] = rsqrtf((float)(degi[i] + 1));
}

// ---------------------------------------------------------------------------
// CSR build: exclusive scan of degi -> rowptr, then cursor-scatter src ids.
__global__ void k_scan_a(const int* __restrict__ degi, int* __restrict__ rowptr,
                         int* __restrict__ csums, int n) {
    __shared__ int sdata[256];
    int tid = threadIdx.x;
    int idx = blockIdx.x * 1024 + tid * 4;
    int v[4];
#pragma unroll
    for (int j = 0; j < 4; ++j) v[j] = (idx + j < n) ? degi[idx + j] : 0;
    int tsum = v[0] + v[1] + v[2] + v[3];
    sdata[tid] = tsum;
    __syncthreads();
    for (int off = 1; off < 256; off <<= 1) {
        int add = (tid >= off) ? sdata[tid - off] : 0;
        __syncthreads();
        sdata[tid] += add;
        __syncthreads();
    }
    int excl = sdata[tid] - tsum;
    int run = 0;
#pragma unroll
    for (int j = 0; j < 4; ++j) {
        if (idx + j < n) rowptr[idx + j] = excl + run;
        run += v[j];
    }
    if (tid == 255) csums[blockIdx.x] = sdata[255];
}

__global__ void k_scan_b(int* __restrict__ csums, int nch) {
    __shared__ int sdata[256];
    int tid = threadIdx.x;
    int v[4];
#pragma unroll
    for (int j = 0; j < 4; ++j) {
        int i = tid * 4 + j;
        v[j] = (i < nch) ? csums[i] : 0;
    }
    int tsum = v[0] + v[1] + v[2] + v[3];
    sdata[tid] = tsum;
    __syncthreads();
    for (int off = 1; off < 256; off <<= 1) {
        int add = (tid >= off) ? sdata[tid - off] : 0;
        __syncthreads();
        sdata[tid] += add;
        __syncthreads();
    }
    int excl = sdata[tid] - tsum;
    int run = 0;
#pragma unroll
    for (int j = 0; j < 4; ++j) {
        int i = tid * 4 + j;
        if (i < nch) csums[i] = excl + run;
        run += v[j];
    }
}

__global__ void k_scan_c(int* __restrict__ rowptr, int* __restrict__ cur,
                         const int* __restrict__ csums, int n, int E) {
    int idx = blockIdx.x * 1024 + threadIdx.x * 4;
    int add = csums[blockIdx.x];
#pragma unroll
    for (int j = 0; j < 4; ++j) {
        if (idx + j < n) {
            int r = rowptr[idx + j] + add;
            rowptr[idx + j] = r;
            cur[idx + j] = r;
        }
    }
    if (blockIdx.x == 0 && threadIdx.x == 0) rowptr[n] = E;
}

// fill, XCD-partitioned by dst range: each XCD's blocks scan all edges and keep
// only dsts in their range -> each esrc cache line is written by ONE XCD, so
// lines accumulate fully in that XCD's L2 and write back once (kills the
// 16x partial-line write amplification). blockIdx&7 -> XCD is a locality
// heuristic only; correctness holds under any mapping.
__global__ void k_fill_xcd(const int* __restrict__ src, const int* __restrict__ dst,
                           int* __restrict__ cur, int* __restrict__ esrc,
                           int E, int N) {
    int xcd = blockIdx.x & 7;
    int lo = (int)((long long)N * xcd / 8);
    int hi = (int)((long long)N * (xcd + 1) / 8);
    int nb = gridDim.x >> 3;
    int bi = blockIdx.x >> 3;
    for (int i = bi * 256 + threadIdx.x; i < E; i += nb * 256) {
        int d = dst[i];
        if (d >= lo && d < hi) {
            int pos = atomicAdd(&cur[d], 1);
            esrc[pos] = src[i];
        }
    }
}

// ---------------------------------------------------------------------------
// K3: T1T[f][c] = bf16( sum_k emb[c][k] * W1[k][f] )   (transposed for MFMA B)
__global__ void k_t1t(const float* __restrict__ emb, const float* __restrict__ W1,
                      short* __restrict__ T1T) {
    int id = blockIdx.x * 256 + threadIdx.x;   // 0..16383
    int f = id >> 7, c = id & 127;
    float acc = 0.f;
#pragma unroll
    for (int k = 0; k < 64; ++k) acc += emb[c * 64 + k] * W1[k * 128 + f];
    T1T[id] = f2bf(acc);
}

// K3b: W2T[f][k] = bf16(W2[k][f])   [64 x 128] transposed for MFMA B
__global__ void k_w2t(const float* __restrict__ W2, short* __restrict__ W2T) {
    int id = blockIdx.x * 256 + threadIdx.x;   // 0..8191
    if (id >= 64 * 128) return;
    int f = id >> 7, k = id & 127;
    W2T[id] = f2bf(W2[k * 64 + f]);
}

// ---------------------------------------------------------------------------
// Fused layer1+layer2 per 16-node tile:
//  1) LDS-atomic vocab histogram w[16][128] from CSR edges (w[d][nid[s]] += dis[s])
//  2) L1 MFMA: relu(dis * (w @ T1) + b1) -> bf16 otile in LDS
//  3) L2 MFMA: g = bf16(dis * (otile @ W2)) -> global (self-loop added in gather)
__global__ __launch_bounds__(256) void k_fused(
        const int* __restrict__ rowptr, const int* __restrict__ esrc,
        const int* __restrict__ nid, const float* __restrict__ dis,
        const short* __restrict__ T1T, const short* __restrict__ W2T,
        const float* __restrict__ b1, unsigned short* __restrict__ g, int N) {
    __shared__ float wtile[16 * WP];
    __shared__ unsigned short otile[16 * OP];
    __shared__ int srp[17];
    int tid = threadIdx.x;
    int v0 = blockIdx.x * 16;
    int nloc = min(16, N - v0);

    if (tid <= nloc) srp[tid] = rowptr[v0 + tid];
    for (int i = tid; i < 16 * WP; i += 256) wtile[i] = 0.f;
    __syncthreads();

    // self loops: w[t][nid[v0+t]] += dis[v0+t]
    if (tid < nloc) {
        int v = v0 + tid;
        atomicAdd(&wtile[tid * WP + nid[v]], dis[v]);
    }
    // edges: contiguous esrc span for these 16 nodes
    int e0 = srp[0], e1 = srp[nloc];
    for (int i = e0 + tid; i < e1; i += 256) {
        int s = esrc[i];
        int lo = 0, hi = nloc;                    // find node owning slot i
        while (hi - lo > 1) {
            int mid = (lo + hi) >> 1;
            if (i >= srp[mid]) lo = mid; else hi = mid;
        }
        atomicAdd(&wtile[lo * WP + nid[s]], dis[s]);
    }
    __syncthreads();

    int wid = tid >> 6, lane = tid & 63;
    int m = lane & 15, g4 = lane >> 4;

    // L1 A-fragments from wtile (f32 -> bf16)
    short8 a[4];
#pragma unroll
    for (int s = 0; s < 4; ++s) {
        float av[8];
        *(f32x4*)(av)     = *(const f32x4*)&wtile[m * WP + g4 * 8 + s * 32];
        *(f32x4*)(av + 4) = *(const f32x4*)&wtile[m * WP + g4 * 8 + s * 32 + 4];
        short8 f;
#pragma unroll
        for (int i = 0; i < 8; ++i) f[i] = f2bf(av[i]);
        a[s] = f;
    }
    float dvals[4];
#pragma unroll
    for (int r = 0; r < 4; ++r) {
        int v = v0 + g4 * 4 + r;
        dvals[r] = (v < N) ? dis[v] : 0.f;
    }

    // L1: each wave computes 2 of 8 feature tiles
#pragma unroll
    for (int t = 0; t < 2; ++t) {
        int nt = wid * 2 + t;
        f32x4 acc = {0.f, 0.f, 0.f, 0.f};
        const short8* bp = (const short8*)(T1T + (size_t)(nt * 16 + m) * 128 + g4 * 8);
#pragma unroll
        for (int s = 0; s < 4; ++s)
            acc = __builtin_amdgcn_mfma_f32_16x16x32_bf16(a[s], bp[s * 4], acc, 0, 0, 0);
        int col = nt * 16 + m;
        float bb = b1[col];
#pragma unroll
        for (int r = 0; r < 4; ++r) {
            int row = g4 * 4 + r;
            otile[row * OP + col] =
                (unsigned short)f2bf(fmaxf(dvals[r] * acc[r] + bb, 0.f));
        }
    }
    __syncthreads();

    // L2: each wave computes 1 of 4 feature tiles (64 outputs)
    short8 a2[4];
#pragma unroll
    for (int s = 0; s < 4; ++s)
        a2[s] = *(const short8*)&otile[m * OP + g4 * 8 + s * 32];
    {
        int nt2 = wid;
        f32x4 acc = {0.f, 0.f, 0.f, 0.f};
        const short8* bp = (const short8*)(W2T + (size_t)(nt2 * 16 + m) * 128 + g4 * 8);
#pragma unroll
        for (int s = 0; s < 4; ++s)
            acc = __builtin_amdgcn_mfma_f32_16x16x32_bf16(a2[s], bp[s * 4], acc, 0, 0, 0);
#pragma unroll
        for (int r = 0; r < 4; ++r) {
            int row = g4 * 4 + r;
            if (row < nloc)
                g[(size_t)(v0 + row) * 64 + nt2 * 16 + m] =
                    (unsigned short)f2bf(dvals[r] * acc[r]);
        }
    }
}

// K7: gather(bf16) + relu + pool. One wave per dst node; lane = feature.
__global__ void k_gather_pool(const int* __restrict__ rowptr, const int* __restrict__ esrc,
                              const unsigned short* __restrict__ g,
                              const float* __restrict__ dis,
                              const float* __restrict__ b2, const int* __restrict__ batch,
                              float* __restrict__ pooled, float* __restrict__ counts,
                              int n) {
    int v = (blockIdx.x * 256 + threadIdx.x) >> 6;
    int lane = threadIdx.x & 63;
    if (v >= n) return;
    int e = rowptr[v], re = rowptr[v + 1];
    float a0 = bf2f(g[(size_t)v * 64 + lane]);   // self loop
    float a1 = 0.f, a2 = 0.f, a3 = 0.f, a4 = 0.f, a5 = 0.f, a6 = 0.f, a7 = 0.f;
    int l8 = lane & 7;
    for (; e + 8 <= re; e += 8) {
        int sl = esrc[e + l8];                    // coalesced; 8 distinct values/wave
        int s0 = __shfl(sl, 0, 8), s1 = __shfl(sl, 1, 8);
        int s2 = __shfl(sl, 2, 8), s3 = __shfl(sl, 3, 8);
        int s4 = __shfl(sl, 4, 8), s5 = __shfl(sl, 5, 8);
        int s6 = __shfl(sl, 6, 8), s7 = __shfl(sl, 7, 8);
        a0 += bf2f(g[(size_t)s0 * 64 + lane]);
        a1 += bf2f(g[(size_t)s1 * 64 + lane]);
        a2 += bf2f(g[(size_t)s2 * 64 + lane]);
        a3 += bf2f(g[(size_t)s3 * 64 + lane]);
        a4 += bf2f(g[(size_t)s4 * 64 + lane]);
        a5 += bf2f(g[(size_t)s5 * 64 + lane]);
        a6 += bf2f(g[(size_t)s6 * 64 + lane]);
        a7 += bf2f(g[(size_t)s7 * 64 + lane]);
    }
    for (; e < re; ++e) a0 += bf2f(g[(size_t)esrc[e] * 64 + lane]);
    float acc = ((a0 + a1) + (a2 + a3)) + ((a4 + a5) + (a6 + a7));
    float x = fmaxf(dis[v] * acc + b2[lane], 0.f);
    int b = batch[v];
    atomicAdd(&pooled[(size_t)b * 64 + lane], x);
    if (lane == 0) atomicAdd(&counts[b], 1.0f);
}

// K8: mean pool + fc + sigmoid  (one wave per graph)
__global__ void k_head(const float* __restrict__ pooled, const float* __restrict__ counts,
                       const float* __restrict__ fc_w, const float* __restrict__ fc_b,
                       float* __restrict__ out, int ngraphs) {
    int gi = (blockIdx.x * 256 + threadIdx.x) >> 6;
    int lane = threadIdx.x & 63;
    if (gi >= ngraphs) return;
    float c = fmaxf(counts[gi], 1.0f);
    float a = (pooled[(size_t)gi * 64 + lane] / c) * fc_w[lane];
#pragma unroll
    for (int off = 32; off >= 1; off >>= 1) a += __shfl_down(a, off);
    if (lane == 0) out[gi] = 1.0f / (1.0f + expf(-(a + fc_b[0])));
}

extern "C" void kernel_launch(void* const* d_in, const int* in_sizes, int n_in,
                              void* d_out, int out_size, void* d_ws, size_t ws_size,
                              hipStream_t stream) {
    const int*   nid   = (const int*)d_in[0];
    const int*   eidx  = (const int*)d_in[1];
    const int*   batch = (const int*)d_in[2];
    const float* emb   = (const float*)d_in[3];
    const float* W1    = (const float*)d_in[4];
    const float* b1    = (const float*)d_in[5];
    const float* W2    = (const float*)d_in[6];
    const float* b2    = (const float*)d_in[7];
    const float* fcw   = (const float*)d_in[8];
    const float* fcb   = (const float*)d_in[9];

    const int N = in_sizes[0];
    const int E = in_sizes[1] / 2;
    const int G = out_size;
    const int* src = eidx;
    const int* dst = eidx + E;

    // workspace carve-out (256B aligned)
    char* p = (char*)d_ws;
    auto alloc = [&](size_t bytes) {
        char* r = p;
        p += (bytes + 255) & ~(size_t)255;
        return r;
    };
    int*   degi   = (int*)  alloc((size_t)N * 4);
    float* dis    = (float*)alloc((size_t)N * 4);
    short* T1T    = (short*)alloc(128 * 128 * 2);
    short* W2T    = (short*)alloc(64 * 128 * 2);
    int*   rowptr = (int*)  alloc((size_t)(N + 1) * 4);
    int*   cur    = (int*)  alloc((size_t)N * 4);
    int*   csums  = (int*)  alloc(4096 * 4);
    int*   esrc   = (int*)  alloc((size_t)E * 4);
    unsigned short* g = (unsigned short*)alloc((size_t)N * 64 * 2);
    float* pooled = (float*)alloc((size_t)G * 64 * 4);
    float* counts = (float*)alloc((size_t)G * 4);

    hipMemsetAsync(degi, 0, (size_t)N * 4, stream);
    hipMemsetAsync(pooled, 0, (size_t)G * 64 * 4, stream);
    hipMemsetAsync(counts, 0, (size_t)G * 4, stream);

    k_deg<<<(E + 255) / 256, 256, 0, stream>>>(dst, degi, E);
    k_dis<<<(N + 255) / 256, 256, 0, stream>>>(degi, dis, N);

    // CSR build
    int nch = (N + 1023) / 1024;
    k_scan_a<<<nch, 256, 0, stream>>>(degi, rowptr, csums, N);
    k_scan_b<<<1, 256, 0, stream>>>(csums, nch);
    k_scan_c<<<nch, 256, 0, stream>>>(rowptr, cur, csums, N, E);
    k_fill_xcd<<<2048, 256, 0, stream>>>(src, dst, cur, esrc, E, N);

    k_t1t<<<64, 256, 0, stream>>>(emb, W1, T1T);
    k_w2t<<<32, 256, 0, stream>>>(W2, W2T);

    k_fused<<<(N + 15) / 16, 256, 0, stream>>>(rowptr, esrc, nid, dis, T1T, W2T,
                                               b1, g, N);

    k_gather_pool<<<((long long)N * 64 + 255) / 256, 256, 0, stream>>>(
        rowptr, esrc, g, dis, b2, batch, pooled, counts, N);
    k_head<<<((long long)G * 64 + 255) / 256, 256, 0, stream>>>(pooled, counts, fcw, fcb,
                                                                (float*)d_out, G);
}

// Round 6
// 285.067 us; speedup vs baseline: 4.2122x; 1.1802x over previous
//
#include <hip/hip_runtime.h>
#include <math.h>

typedef short short8 __attribute__((ext_vector_type(8)));
typedef float f32x4 __attribute__((ext_vector_type(4)));

#define WP 132   // wtile pitch (f32)
#define OP 136   // otile pitch (bf16)

__device__ __forceinline__ short f2bf(float x) {
    unsigned u = __float_as_uint(x);
    u += 0x7fffu + ((u >> 16) & 1u);
    return (short)(u >> 16);
}
__device__ __forceinline__ float bf2f(unsigned short u) {
    return __uint_as_float(((unsigned)u) << 16);
}

// ---------------------------------------------------------------------------
// K1: in-degree histogram (real edges only; self-loop added as +1 in scan_a)
__global__ void k_deg(const int* __restrict__ dst, int* __restrict__ degi, int E) {
    int i = blockIdx.x * 256 + threadIdx.x;
    if (i < E) atomicAdd(&degi[dst[i]], 1);
}

// ---------------------------------------------------------------------------
// CSR build. scan_a also emits dis = rsqrt(deg+1).
__global__ void k_scan_a(const int* __restrict__ degi, int* __restrict__ rowptr,
                         int* __restrict__ csums, float* __restrict__ dis, int n) {
    __shared__ int sdata[256];
    int tid = threadIdx.x;
    int idx = blockIdx.x * 1024 + tid * 4;
    int v[4];
#pragma unroll
    for (int j = 0; j < 4; ++j) {
        v[j] = (idx + j < n) ? degi[idx + j] : 0;
        if (idx + j < n) dis[idx + j] = rsqrtf((float)(v[j] + 1));
    }
    int tsum = v[0] + v[1] + v[2] + v[3];
    sdata[tid] = tsum;
    __syncthreads();
    for (int off = 1; off < 256; off <<= 1) {
        int add = (tid >= off) ? sdata[tid - off] : 0;
        __syncthreads();
        sdata[tid] += add;
        __syncthreads();
    }
    int excl = sdata[tid] - tsum;
    int run = 0;
#pragma unroll
    for (int j = 0; j < 4; ++j) {
        if (idx + j < n) rowptr[idx + j] = excl + run;
        run += v[j];
    }
    if (tid == 255) csums[blockIdx.x] = sdata[255];
}

__global__ void k_scan_b(int* __restrict__ csums, int nch) {
    __shared__ int sdata[256];
    int tid = threadIdx.x;
    int v[4];
#pragma unroll
    for (int j = 0; j < 4; ++j) {
        int i = tid * 4 + j;
        v[j] = (i < nch) ? csums[i] : 0;
    }
    int tsum = v[0] + v[1] + v[2] + v[3];
    sdata[tid] = tsum;
    __syncthreads();
    for (int off = 1; off < 256; off <<= 1) {
        int add = (tid >= off) ? sdata[tid - off] : 0;
        __syncthreads();
        sdata[tid] += add;
        __syncthreads();
    }
    int excl = sdata[tid] - tsum;
    int run = 0;
#pragma unroll
    for (int j = 0; j < 4; ++j) {
        int i = tid * 4 + j;
        if (i < nch) csums[i] = excl + run;
        run += v[j];
    }
}

__global__ void k_scan_c(int* __restrict__ rowptr, int* __restrict__ cur,
                         const int* __restrict__ csums, int n, int E) {
    int idx = blockIdx.x * 1024 + threadIdx.x * 4;
    int add = csums[blockIdx.x];
#pragma unroll
    for (int j = 0; j < 4; ++j) {
        if (idx + j < n) {
            int r = rowptr[idx + j] + add;
            rowptr[idx + j] = r;
            cur[idx + j] = r;
        }
    }
    if (blockIdx.x == 0 && threadIdx.x == 0) rowptr[n] = E;
}

// fill, XCD-partitioned by dst range (locality heuristic; correctness holds
// under any blockIdx->XCD mapping).
__global__ void k_fill_xcd(const int* __restrict__ src, const int* __restrict__ dst,
                           int* __restrict__ cur, int* __restrict__ esrc,
                           int E, int N) {
    int xcd = blockIdx.x & 7;
    int lo = (int)((long long)N * xcd / 8);
    int hi = (int)((long long)N * (xcd + 1) / 8);
    int nb = gridDim.x >> 3;
    int bi = blockIdx.x >> 3;
    for (int i = bi * 256 + threadIdx.x; i < E; i += nb * 256) {
        int d = dst[i];
        if (d >= lo && d < hi) {
            int pos = atomicAdd(&cur[d], 1);
            esrc[pos] = src[i];
        }
    }
}

// ---------------------------------------------------------------------------
// Weight tables: T1T[f][c] = bf16((emb@W1)^T), W2T[f][k] = bf16(W2^T)
__global__ void k_tabs(const float* __restrict__ emb, const float* __restrict__ W1,
                       const float* __restrict__ W2,
                       short* __restrict__ T1T, short* __restrict__ W2T) {
    int id = blockIdx.x * 256 + threadIdx.x;
    if (id < 128 * 128) {
        int f = id >> 7, c = id & 127;
        float acc = 0.f;
#pragma unroll
        for (int k = 0; k < 64; ++k) acc += emb[c * 64 + k] * W1[k * 128 + f];
        T1T[id] = f2bf(acc);
    } else {
        int id2 = id - 128 * 128;
        if (id2 < 64 * 128) {
            int f = id2 >> 7, k = id2 & 127;
            W2T[id2] = f2bf(W2[k * 64 + f]);
        }
    }
}

// ---------------------------------------------------------------------------
// Fused layer1+layer2 per 16-node tile (LDS vocab histogram -> MFMA -> MFMA)
__global__ __launch_bounds__(256) void k_fused(
        const int* __restrict__ rowptr, const int* __restrict__ esrc,
        const int* __restrict__ nid, const float* __restrict__ dis,
        const short* __restrict__ T1T, const short* __restrict__ W2T,
        const float* __restrict__ b1, unsigned short* __restrict__ g, int N) {
    __shared__ float wtile[16 * WP];
    __shared__ unsigned short otile[16 * OP];
    __shared__ int srp[17];
    int tid = threadIdx.x;
    int v0 = blockIdx.x * 16;
    int nloc = min(16, N - v0);

    if (tid <= nloc) srp[tid] = rowptr[v0 + tid];
    for (int i = tid; i < 16 * WP; i += 256) wtile[i] = 0.f;
    __syncthreads();

    if (tid < nloc) {                       // self loops
        int v = v0 + tid;
        atomicAdd(&wtile[tid * WP + nid[v]], dis[v]);
    }
    int e0 = srp[0], e1 = srp[nloc];
    for (int i = e0 + tid; i < e1; i += 256) {
        int s = esrc[i];
        int lo = 0, hi = nloc;
        while (hi - lo > 1) {
            int mid = (lo + hi) >> 1;
            if (i >= srp[mid]) lo = mid; else hi = mid;
        }
        atomicAdd(&wtile[lo * WP + nid[s]], dis[s]);
    }
    __syncthreads();

    int wid = tid >> 6, lane = tid & 63;
    int m = lane & 15, g4 = lane >> 4;

    short8 a[4];
#pragma unroll
    for (int s = 0; s < 4; ++s) {
        float av[8];
        *(f32x4*)(av)     = *(const f32x4*)&wtile[m * WP + g4 * 8 + s * 32];
        *(f32x4*)(av + 4) = *(const f32x4*)&wtile[m * WP + g4 * 8 + s * 32 + 4];
        short8 f;
#pragma unroll
        for (int i = 0; i < 8; ++i) f[i] = f2bf(av[i]);
        a[s] = f;
    }
    float dvals[4];
#pragma unroll
    for (int r = 0; r < 4; ++r) {
        int v = v0 + g4 * 4 + r;
        dvals[r] = (v < N) ? dis[v] : 0.f;
    }

#pragma unroll
    for (int t = 0; t < 2; ++t) {
        int nt = wid * 2 + t;
        f32x4 acc = {0.f, 0.f, 0.f, 0.f};
        const short8* bp = (const short8*)(T1T + (size_t)(nt * 16 + m) * 128 + g4 * 8);
#pragma unroll
        for (int s = 0; s < 4; ++s)
            acc = __builtin_amdgcn_mfma_f32_16x16x32_bf16(a[s], bp[s * 4], acc, 0, 0, 0);
        int col = nt * 16 + m;
        float bb = b1[col];
#pragma unroll
        for (int r = 0; r < 4; ++r) {
            int row = g4 * 4 + r;
            otile[row * OP + col] =
                (unsigned short)f2bf(fmaxf(dvals[r] * acc[r] + bb, 0.f));
        }
    }
    __syncthreads();

    short8 a2[4];
#pragma unroll
    for (int s = 0; s < 4; ++s)
        a2[s] = *(const short8*)&otile[m * OP + g4 * 8 + s * 32];
    {
        int nt2 = wid;
        f32x4 acc = {0.f, 0.f, 0.f, 0.f};
        const short8* bp = (const short8*)(W2T + (size_t)(nt2 * 16 + m) * 128 + g4 * 8);
#pragma unroll
        for (int s = 0; s < 4; ++s)
            acc = __builtin_amdgcn_mfma_f32_16x16x32_bf16(a2[s], bp[s * 4], acc, 0, 0, 0);
#pragma unroll
        for (int r = 0; r < 4; ++r) {
            int row = g4 * 4 + r;
            if (row < nloc)
                g[(size_t)(v0 + row) * 64 + nt2 * 16 + m] =
                    (unsigned short)f2bf(dvals[r] * acc[r]);
        }
    }
}

// ---------------------------------------------------------------------------
// K7: gather(bf16) + relu -> x (f32, coalesced write; NO atomics).
// Half-wave scheme: each 32-lane half gathers a different row via 4B loads
// (lane l32 covers features 2*l32, 2*l32+1) -> 16 rows in flight per wave.
__global__ void k_gather(const int* __restrict__ rowptr, const int* __restrict__ esrc,
                         const unsigned short* __restrict__ g,
                         const float* __restrict__ dis, const float* __restrict__ b2,
                         float* __restrict__ x, int n) {
    int v = (blockIdx.x * 256 + threadIdx.x) >> 6;
    int lane = threadIdx.x & 63;
    if (v >= n) return;
    const unsigned* g32 = (const unsigned*)g;
    int half = lane >> 5, l32 = lane & 31;

    float2 a0 = {0.f, 0.f}, a1 = {0.f, 0.f}, a2 = {0.f, 0.f}, a3 = {0.f, 0.f};
    float2 a4 = {0.f, 0.f}, a5 = {0.f, 0.f}, a6 = {0.f, 0.f}, a7 = {0.f, 0.f};

    if (half == 0) {                         // self loop (row v) on half 0
        unsigned u = g32[(size_t)v * 32 + l32];
        a7.x += __uint_as_float(u << 16);
        a7.y += __uint_as_float(u & 0xffff0000u);
    }
    int e = rowptr[v], re = rowptr[v + 1];
    for (; e + 16 <= re; e += 16) {
        int sl = esrc[e + (lane & 15)];      // 16 ids, coalesced
        int s0 = __shfl(sl, 0 + half, 16), s1 = __shfl(sl, 2 + half, 16);
        int s2 = __shfl(sl, 4 + half, 16), s3 = __shfl(sl, 6 + half, 16);
        int s4 = __shfl(sl, 8 + half, 16), s5 = __shfl(sl, 10 + half, 16);
        int s6 = __shfl(sl, 12 + half, 16), s7 = __shfl(sl, 14 + half, 16);
        unsigned u0 = g32[(size_t)s0 * 32 + l32];
        unsigned u1 = g32[(size_t)s1 * 32 + l32];
        unsigned u2 = g32[(size_t)s2 * 32 + l32];
        unsigned u3 = g32[(size_t)s3 * 32 + l32];
        unsigned u4 = g32[(size_t)s4 * 32 + l32];
        unsigned u5 = g32[(size_t)s5 * 32 + l32];
        unsigned u6 = g32[(size_t)s6 * 32 + l32];
        unsigned u7 = g32[(size_t)s7 * 32 + l32];
        a0.x += __uint_as_float(u0 << 16); a0.y += __uint_as_float(u0 & 0xffff0000u);
        a1.x += __uint_as_float(u1 << 16); a1.y += __uint_as_float(u1 & 0xffff0000u);
        a2.x += __uint_as_float(u2 << 16); a2.y += __uint_as_float(u2 & 0xffff0000u);
        a3.x += __uint_as_float(u3 << 16); a3.y += __uint_as_float(u3 & 0xffff0000u);
        a4.x += __uint_as_float(u4 << 16); a4.y += __uint_as_float(u4 & 0xffff0000u);
        a5.x += __uint_as_float(u5 << 16); a5.y += __uint_as_float(u5 & 0xffff0000u);
        a6.x += __uint_as_float(u6 << 16); a6.y += __uint_as_float(u6 & 0xffff0000u);
        a7.x += __uint_as_float(u7 << 16); a7.y += __uint_as_float(u7 & 0xffff0000u);
    }
    for (; e + 2 <= re; e += 2) {            // pair tail: one row per half
        int s = esrc[e + half];
        unsigned u = g32[(size_t)s * 32 + l32];
        a0.x += __uint_as_float(u << 16);
        a0.y += __uint_as_float(u & 0xffff0000u);
    }
    if (e < re && half == 0) {               // single tail
        int s = esrc[e];
        unsigned u = g32[(size_t)s * 32 + l32];
        a1.x += __uint_as_float(u << 16);
        a1.y += __uint_as_float(u & 0xffff0000u);
    }
    float2 tot;
    tot.x = ((a0.x + a1.x) + (a2.x + a3.x)) + ((a4.x + a5.x) + (a6.x + a7.x));
    tot.y = ((a0.y + a1.y) + (a2.y + a3.y)) + ((a4.y + a5.y) + (a6.y + a7.y));
    tot.x += __shfl_xor(tot.x, 32);          // combine halves
    tot.y += __shfl_xor(tot.y, 32);
    if (half == 0) {
        float dv = dis[v];
        float2 bb = ((const float2*)b2)[l32];
        float2 r;
        r.x = fmaxf(dv * tot.x + bb.x, 0.f);
        r.y = fmaxf(dv * tot.y + bb.y, 0.f);
        ((float2*)(x + (size_t)v * 64))[l32] = r;
    }
}

// ---------------------------------------------------------------------------
// Graph boundaries from sorted batch (gstart/gend pre-zeroed for empty graphs)
__global__ void k_bounds(const int* __restrict__ batch, int* __restrict__ gstart,
                         int* __restrict__ gend, int n) {
    int i = blockIdx.x * 256 + threadIdx.x;
    if (i >= n) return;
    int b = batch[i];
    if (i == 0 || batch[i - 1] != b) gstart[b] = i;
    if (i == n - 1 || batch[i + 1] != b) gend[b] = i + 1;
}

// Pool + fc + sigmoid: one block per graph, coalesced segment mean, no atomics
__global__ __launch_bounds__(256) void k_pool2(
        const float* __restrict__ x, const int* __restrict__ gstart,
        const int* __restrict__ gend, const float* __restrict__ fc_w,
        const float* __restrict__ fc_b, float* __restrict__ out) {
    __shared__ float red[4][64];
    int gi = blockIdx.x;
    int tid = threadIdx.x, wid = tid >> 6, lane = tid & 63;
    int s = gstart[gi], epos = gend[gi];
    float acc = 0.f;
    for (int r = s + wid; r < epos; r += 4) acc += x[(size_t)r * 64 + lane];
    red[wid][lane] = acc;
    __syncthreads();
    if (wid == 0) {
        float a = red[0][lane] + red[1][lane] + red[2][lane] + red[3][lane];
        float cnt = fmaxf((float)(epos - s), 1.0f);
        a = (a / cnt) * fc_w[lane];
#pragma unroll
        for (int off = 32; off >= 1; off >>= 1) a += __shfl_down(a, off);
        if (lane == 0) out[gi] = 1.0f / (1.0f + expf(-(a + fc_b[0])));
    }
}

extern "C" void kernel_launch(void* const* d_in, const int* in_sizes, int n_in,
                              void* d_out, int out_size, void* d_ws, size_t ws_size,
                              hipStream_t stream) {
    const int*   nid   = (const int*)d_in[0];
    const int*   eidx  = (const int*)d_in[1];
    const int*   batch = (const int*)d_in[2];
    const float* emb   = (const float*)d_in[3];
    const float* W1    = (const float*)d_in[4];
    const float* b1    = (const float*)d_in[5];
    const float* W2    = (const float*)d_in[6];
    const float* b2    = (const float*)d_in[7];
    const float* fcw   = (const float*)d_in[8];
    const float* fcb   = (const float*)d_in[9];

    const int N = in_sizes[0];
    const int E = in_sizes[1] / 2;
    const int G = out_size;
    const int* src = eidx;
    const int* dst = eidx + E;

    char* p = (char*)d_ws;
    auto alloc = [&](size_t bytes) {
        char* r = p;
        p += (bytes + 255) & ~(size_t)255;
        return r;
    };
    int*   degi   = (int*)  alloc((size_t)N * 4);
    float* dis    = (float*)alloc((size_t)N * 4);
    short* T1T    = (short*)alloc(128 * 128 * 2);
    short* W2T    = (short*)alloc(64 * 128 * 2);
    int*   rowptr = (int*)  alloc((size_t)(N + 1) * 4);
    int*   cur    = (int*)  alloc((size_t)N * 4);
    int*   csums  = (int*)  alloc(4096 * 4);
    int*   esrc   = (int*)  alloc((size_t)E * 4);
    unsigned short* g = (unsigned short*)alloc((size_t)N * 64 * 2);
    float* x      = (float*)alloc((size_t)N * 64 * 4);
    int*   gstart = (int*)  alloc((size_t)G * 4);
    int*   gend   = (int*)  alloc((size_t)G * 4);

    hipMemsetAsync(degi, 0, (size_t)N * 4, stream);
    hipMemsetAsync(gstart, 0, (size_t)G * 4, stream);
    hipMemsetAsync(gend, 0, (size_t)G * 4, stream);

    k_deg<<<(E + 255) / 256, 256, 0, stream>>>(dst, degi, E);

    int nch = (N + 1023) / 1024;
    k_scan_a<<<nch, 256, 0, stream>>>(degi, rowptr, csums, dis, N);
    k_scan_b<<<1, 256, 0, stream>>>(csums, nch);
    k_scan_c<<<nch, 256, 0, stream>>>(rowptr, cur, csums, N, E);
    k_fill_xcd<<<2048, 256, 0, stream>>>(src, dst, cur, esrc, E, N);

    k_tabs<<<96, 256, 0, stream>>>(emb, W1, W2, T1T, W2T);

    k_fused<<<(N + 15) / 16, 256, 0, stream>>>(rowptr, esrc, nid, dis, T1T, W2T,
                                               b1, g, N);

    k_gather<<<((long long)N * 64 + 255) / 256, 256, 0, stream>>>(
        rowptr, esrc, g, dis, b2, x, N);

    k_bounds<<<(N + 255) / 256, 256, 0, stream>>>(batch, gstart, gend, N);
    k_pool2<<<G, 256, 0, stream>>>(x, gstart, gend, fcw, fcb, (float*)d_out);
}